// Round 5
// baseline (327.957 us; speedup 1.0000x reference)
//
#include <hip/hip_runtime.h>
#include <hip/hip_bf16.h>
#include <stdint.h>

typedef __attribute__((ext_vector_type(8))) short short8;
typedef __attribute__((ext_vector_type(4))) float f32x4;
typedef __attribute__((ext_vector_type(4))) unsigned short ushort4x;

#define T_DIM 256
#define NBATCH 64

__device__ __forceinline__ void gload_lds16(const void* g, void* l) {
    __builtin_amdgcn_global_load_lds(
        (const __attribute__((address_space(1))) void*)g,
        (__attribute__((address_space(3))) void*)l, 16, 0, 0);
}

// ---------------- prep: W [(K+1)][O] fp32 -> WT_hi/WT_lo [O][K] bf16 + bias[O] ----
__global__ void prep_w(const float* __restrict__ W, __hip_bfloat16* __restrict__ WTh,
                       __hip_bfloat16* __restrict__ WTl, float* __restrict__ bias,
                       int K, int O) {
    int idx = blockIdx.x * blockDim.x + threadIdx.x;
    int total = O * K;
    if (idx < total) {
        int o = idx / K, i = idx % K;
        float w = W[(size_t)i * O + o];
        __hip_bfloat16 h = __float2bfloat16(w);
        WTh[idx] = h;
        WTl[idx] = __float2bfloat16(w - __bfloat162float(h));
    }
    if (idx < O) bias[idx] = W[(size_t)K * O + idx];
}

// ---------------- prep: x [64][512][256] fp32 -> xh/xl [64][256][512] bf16 --------
__global__ void prep_x(const float* __restrict__ x, __hip_bfloat16* __restrict__ xh,
                       __hip_bfloat16* __restrict__ xl) {
    __shared__ float tile[32][33];
    int b = blockIdx.z;
    int i0 = blockIdx.x * 32;   // input-dim 512
    int t0 = blockIdx.y * 32;   // time 256
    int tx = threadIdx.x;       // 0..31
    int ty = threadIdx.y;       // 0..7
    for (int dy = 0; dy < 32; dy += 8)
        tile[ty + dy][tx] = x[((size_t)b * 512 + i0 + ty + dy) * T_DIM + t0 + tx];
    __syncthreads();
    for (int dy = 0; dy < 32; dy += 8) {
        float w = tile[tx][ty + dy];
        size_t dst = ((size_t)b * T_DIM + t0 + ty + dy) * 512 + i0 + tx;
        __hip_bfloat16 h = __float2bfloat16(w);
        xh[dst] = h;
        xl[dst] = __float2bfloat16(w - __bfloat162float(h));
    }
}

// ---------------- 256x256 counted-vmcnt pipelined GEMM (layers 1 & 2) -------------
// pre[b][t][o] = sum_p A_p[o][:]·B_p[b][t][:] + bias[o].  Tile 256(o) x 256(t=all),
// BK=64, 8 waves (2M x 4N), per-wave 128x64, acc[8][4].  LDS 128KB = 2 x {A 32KB,
// B 32KB} double-buffer.  Depth-2 pipeline with RAW s_barrier + counted vmcnt(8)
// (never __syncthreads: its vmcnt(0) drain is the m97 stall).  K flattened across
// planes: step -> (p = step>>KSHIFT, k0 = (step&mask)*64); accumulation order per
// output element identical to the 2-barrier kernel -> bit-identical results.
template <int NT, int KSHIFT>
__global__ __launch_bounds__(512, 2) void gemm256(
    const __hip_bfloat16* __restrict__ A0, const __hip_bfloat16* __restrict__ A1,
    const __hip_bfloat16* __restrict__ A2,
    const __hip_bfloat16* __restrict__ B0, const __hip_bfloat16* __restrict__ B1,
    const __hip_bfloat16* __restrict__ B2,
    const float* __restrict__ bias, float* __restrict__ Cout,
    int O, int nOx) {
    constexpr int K = 64 << KSHIFT;
    __shared__ __align__(16) char lds[131072];

    // XCD mapping: xcd = fid&7 owns batches [xcd*8, xcd*8+8)
    const int fid = blockIdx.x;
    const int xcd = fid & 7;
    const int k_in = fid >> 3;
    const int b = xcd * 8 + k_in / nOx;
    const int o0 = (k_in % nOx) * 256;

    const int tid = threadIdx.x;
    const int lane = tid & 63;
    const int wave = tid >> 6;   // 0..7
    const int wm = wave >> 2;    // 0..1 (o)
    const int wn = wave & 3;     // 0..3 (t)

    const int srow = tid >> 3;         // 0..63
    const int skb = (tid & 7) * 16;    // linear LDS dest byte in 128B row
    const int src_x = skb ^ ((srow & 7) << 4);  // pre-swizzled global column

    f32x4 acc[8][4] = {};

    // stage K-tile `step` (A: 256x64, B: 256x64) into buffer `buf` (8 loads/thread)
    auto STAGE = [&](int step, int buf) {
        int p = step >> KSHIFT;
        int k0 = (step & ((1 << KSHIFT) - 1)) << 6;
        const __hip_bfloat16* Aq = (p == 0) ? A0 : ((p == 1) ? A1 : A2);
        const __hip_bfloat16* Bq = (p == 0) ? B0 : ((p == 1) ? B1 : B2);
        const char* Ag = (const char*)(Aq + (size_t)(o0 + srow) * K + k0) + src_x;
        const char* Bg = (const char*)(Bq + ((size_t)b * T_DIM + srow) * K + k0) + src_x;
        char* Ad = lds + buf * 65536 + srow * 128 + skb;
        char* Bd = Ad + 32768;
#pragma unroll
        for (int r = 0; r < 4; ++r) {
            gload_lds16(Ag + (size_t)128 * K * r, Ad + 8192 * r);  // 64 rows per r
            gload_lds16(Bg + (size_t)128 * K * r, Bd + 8192 * r);
        }
    };

    STAGE(0, 0);
    STAGE(1, 1);   // 16 loads outstanding

    for (int step = 0; step < NT; ++step) {
        const int cur = step & 1;
        // counted wait: oldest 8 (this buffer's loads) landed; next tile's 8 fly on
        if (step == NT - 1)
            asm volatile("s_waitcnt vmcnt(0)" ::: "memory");
        else
            asm volatile("s_waitcnt vmcnt(8)" ::: "memory");
        __builtin_amdgcn_s_barrier();      // all waves' stage loads landed
        __builtin_amdgcn_sched_barrier(0); // no ds_read hoisted above this point

        const char* Ab = lds + cur * 65536;
        const char* Bb = Ab + 32768;
        short8 bfr[4][2];
#pragma unroll
        for (int j = 0; j < 4; ++j) {
            int row = wn * 64 + j * 16 + (lane & 15);
#pragma unroll
            for (int kk = 0; kk < 2; ++kk) {
                int kb = ((((lane >> 4) * 8) + kk * 32) * 2) ^ ((row & 7) << 4);
                bfr[j][kk] = *(const short8*)(Bb + row * 128 + kb);
            }
        }
        __builtin_amdgcn_s_setprio(1);
#pragma unroll
        for (int q = 0; q < 4; ++q) {      // 4 M-quadrant phases x 16 MFMA
            short8 af[2][2];
#pragma unroll
            for (int i = 0; i < 2; ++i) {
                int row = wm * 128 + (q * 2 + i) * 16 + (lane & 15);
#pragma unroll
                for (int kk = 0; kk < 2; ++kk) {
                    int kb = ((((lane >> 4) * 8) + kk * 32) * 2) ^ ((row & 7) << 4);
                    af[i][kk] = *(const short8*)(Ab + row * 128 + kb);
                }
            }
#pragma unroll
            for (int kk = 0; kk < 2; ++kk)
#pragma unroll
                for (int i = 0; i < 2; ++i)
#pragma unroll
                    for (int j = 0; j < 4; ++j)
                        acc[q * 2 + i][j] = __builtin_amdgcn_mfma_f32_16x16x32_bf16(
                            af[i][kk], bfr[j][kk], acc[q * 2 + i][j], 0, 0, 0);
        }
        __builtin_amdgcn_s_setprio(0);
        __builtin_amdgcn_sched_barrier(0); // keep all reads of buf[cur] above
        __builtin_amdgcn_s_barrier();      // all waves done reading buf[cur]
        __builtin_amdgcn_sched_barrier(0);
        if (step + 2 < NT) STAGE(step + 2, cur);  // refill the freed buffer
    }

    // epilogue: D col(t)=lane&15, row(o)=(lane>>4)*4+r -> float4/lane into [b][t][o]
#pragma unroll
    for (int i = 0; i < 8; ++i) {
        int ob = o0 + wm * 128 + i * 16 + ((lane >> 4) * 4);
        f32x4 bv = *(const f32x4*)(bias + ob);
#pragma unroll
        for (int j = 0; j < 4; ++j) {
            int t = wn * 64 + j * 16 + (lane & 15);
            *(f32x4*)(Cout + ((size_t)b * T_DIM + t) * O + ob) = acc[i][j] + bv;
        }
    }
}

// ---------------- 128 x BN GEMM (layer 3: O=256 needs more blocks) ----------------
template <int BN>
__global__ __launch_bounds__(256) void gemm_mfma(
    const __hip_bfloat16* __restrict__ A0, const __hip_bfloat16* __restrict__ A1,
    const __hip_bfloat16* __restrict__ A2,
    const __hip_bfloat16* __restrict__ B0, const __hip_bfloat16* __restrict__ B1,
    const __hip_bfloat16* __restrict__ B2,
    const float* __restrict__ bias, float* __restrict__ Cout,
    int O, int K, int npass, int nOx, int nTy) {
    constexpr int NB = BN / 32;
    __shared__ __hip_bfloat16 As[128 * 64];
    __shared__ __hip_bfloat16 Bs[BN * 64];

    const int fid = blockIdx.x;
    const int bpb = nOx * nTy;
    const int xcd = fid & 7;
    const int k_in = fid >> 3;
    const int b = xcd * 8 + k_in / bpb;
    const int r_in = k_in % bpb;
    const int o0 = (r_in / nTy) * 128;
    const int t0 = (r_in % nTy) * BN;

    const int tid = threadIdx.x;
    const int lane = tid & 63;
    const int wave = tid >> 6;
    const int wm = wave >> 1, wn = wave & 1;

    const __hip_bfloat16* Ap[3] = {A0, A1, A2};
    const __hip_bfloat16* Bp[3] = {B0, B1, B2};

    f32x4 acc[4][NB] = {};

    const int srow = tid >> 3;
    const int skb  = (tid & 7) * 16;

    for (int p = 0; p < npass; ++p) {
        const __hip_bfloat16* Aptr = Ap[p];
        const __hip_bfloat16* Bptr = Bp[p] + (size_t)b * T_DIM * K;
        for (int k0 = 0; k0 < K; k0 += 64) {
            int src_kb = skb ^ ((srow & 7) << 4);
#pragma unroll
            for (int r = 0; r < 4; ++r) {
                int row = srow + r * 32;
                gload_lds16((const char*)(Aptr + (size_t)(o0 + row) * K + k0) + src_kb,
                            (char*)As + row * 128 + skb);
            }
#pragma unroll
            for (int r = 0; r < NB; ++r) {
                int row = srow + r * 32;
                gload_lds16((const char*)(Bptr + (size_t)(t0 + row) * K + k0) + src_kb,
                            (char*)Bs + row * 128 + skb);
            }
            __syncthreads();
#pragma unroll
            for (int kk = 0; kk < 2; ++kk) {
                short8 af[4], bfr[NB];
#pragma unroll
                for (int i = 0; i < 4; ++i) {
                    int row = wm * 64 + i * 16 + (lane & 15);
                    int kb = ((((lane >> 4) * 8) + kk * 32) * 2) ^ ((row & 7) << 4);
                    af[i] = *(const short8*)((const char*)As + row * 128 + kb);
                }
#pragma unroll
                for (int j = 0; j < NB; ++j) {
                    int row = wn * (BN / 2) + j * 16 + (lane & 15);
                    int kb = ((((lane >> 4) * 8) + kk * 32) * 2) ^ ((row & 7) << 4);
                    bfr[j] = *(const short8*)((const char*)Bs + row * 128 + kb);
                }
#pragma unroll
                for (int i = 0; i < 4; ++i)
#pragma unroll
                    for (int j = 0; j < NB; ++j)
                        acc[i][j] = __builtin_amdgcn_mfma_f32_16x16x32_bf16(
                            af[i], bfr[j], acc[i][j], 0, 0, 0);
            }
            __syncthreads();
        }
    }
#pragma unroll
    for (int i = 0; i < 4; ++i) {
        int ob = o0 + wm * 64 + i * 16 + ((lane >> 4) * 4);
        f32x4 bv = *(const f32x4*)(bias + ob);
#pragma unroll
        for (int j = 0; j < NB; ++j) {
            int t = t0 + wn * (BN / 2) + j * 16 + (lane & 15);
            f32x4 v = acc[i][j] + bv;
            *(f32x4*)(Cout + ((size_t)b * T_DIM + t) * O + ob) = v;
        }
    }
}

// ---------------- LIF scan: hidden layers, 4 neurons/thread -----------------------
// pre [b][t][o] fp32 -> spikes S [b][t][o] bf16.  float4 loads, short4 stores.
__global__ void lif_hidden4(const float* __restrict__ pre, __hip_bfloat16* __restrict__ st,
                            const float* __restrict__ beta_p, const float* __restrict__ thr_p,
                            int O) {
    int idx = blockIdx.x * blockDim.x + threadIdx.x;   // (b*O + o)/4
    int og = O >> 2;
    int b = idx / og, o4 = (idx - b * og) * 4;
    float sb = 1.f / (1.f + expf(-beta_p[0]));
    float thr = thr_p[0];
    float m0 = 0.f, m1 = 0.f, m2 = 0.f, m3 = 0.f;
    const float* src = pre + (size_t)b * T_DIM * O + o4;
    __hip_bfloat16* dst = st + (size_t)b * T_DIM * O + o4;
    for (int t = 0; t < T_DIM; ++t) {
        f32x4 v = *(const f32x4*)(src + (size_t)t * O);
        float u0 = __fadd_rn(__fmul_rn(sb, m0), v[0]);
        float u1 = __fadd_rn(__fmul_rn(sb, m1), v[1]);
        float u2 = __fadd_rn(__fmul_rn(sb, m2), v[2]);
        float u3 = __fadd_rn(__fmul_rn(sb, m3), v[3]);
        ushort4x s;
        s.x = (u0 >= thr) ? 0x3F80 : 0;   // bf16(1.0) / bf16(0.0)
        s.y = (u1 >= thr) ? 0x3F80 : 0;
        s.z = (u2 >= thr) ? 0x3F80 : 0;
        s.w = (u3 >= thr) ? 0x3F80 : 0;
        m0 = u0 - (s.x ? thr : 0.f);
        m1 = u1 - (s.y ? thr : 0.f);
        m2 = u2 - (s.z ? thr : 0.f);
        m3 = u3 - (s.w ? thr : 0.f);
        *(ushort4x*)(dst + (size_t)t * O) = s;
    }
}

// ---------------- LIF scan: final layer (LDS-transposed coalesced writes) ---------
__global__ __launch_bounds__(64) void lif_final_t(
    const float* __restrict__ pre, float* __restrict__ osp, float* __restrict__ omem,
    const float* __restrict__ beta_p, const float* __restrict__ thr_p) {
    __shared__ float spk[64][33];
    __shared__ float mm[64][33];
    int bid = blockIdx.x;          // 0..255
    int b = bid >> 2, og = bid & 3;
    int lane = threadIdx.x;        // 0..63
    float sb = 1.f / (1.f + expf(-beta_p[0]));
    float thr = thr_p[0];
    float mem = 0.f;
    const float* src = pre + (size_t)b * T_DIM * 256 + og * 64 + lane;
    int bo = b * 256 + og * 64;
    for (int c = 0; c < 8; ++c) {
        int t0 = c * 32;
        float xv[32];
#pragma unroll
        for (int tt = 0; tt < 32; ++tt)
            xv[tt] = src[(size_t)(t0 + tt) * 256];
#pragma unroll
        for (int tt = 0; tt < 32; ++tt) {
            mm[lane][tt] = mem;
            float mu = __fadd_rn(__fmul_rn(sb, mem), xv[tt]);
            float spike = (mu >= thr) ? 1.f : 0.f;
            spk[lane][tt] = spike;
            mem = mu - spike * thr;
        }
#pragma unroll
        for (int it = 0; it < 32; ++it) {
            int row = (lane >> 5) + 2 * it;
            int col = lane & 31;
            size_t dst = ((size_t)bo + row) * T_DIM + t0 + col;
            osp[dst] = spk[row][col];
            omem[dst] = mm[row][col];
        }
    }
}

extern "C" void kernel_launch(void* const* d_in, const int* in_sizes, int n_in,
                              void* d_out, int out_size, void* d_ws, size_t ws_size,
                              hipStream_t stream) {
    const float* x  = (const float*)d_in[0];
    const float* W0 = (const float*)d_in[1];
    const float* W1 = (const float*)d_in[2];
    const float* W2 = (const float*)d_in[3];
    const float* beta = (const float*)d_in[4];
    const float* thr  = (const float*)d_in[5];
    float* out = (float*)d_out;

    char* ws = (char*)d_ws;
    size_t off = 0;
    auto alloc = [&](size_t bytes) {
        size_t r = off;
        off = (off + bytes + 255) & ~(size_t)255;
        return r;
    };
    __hip_bfloat16* w0h = (__hip_bfloat16*)(ws + alloc(1024 * 512 * 2));
    __hip_bfloat16* w0l = (__hip_bfloat16*)(ws + alloc(1024 * 512 * 2));
    float* b0 = (float*)(ws + alloc(1024 * 4));
    __hip_bfloat16* w1h = (__hip_bfloat16*)(ws + alloc(1024 * 1024 * 2));
    __hip_bfloat16* w1l = (__hip_bfloat16*)(ws + alloc(1024 * 1024 * 2));
    float* b1 = (float*)(ws + alloc(1024 * 4));
    __hip_bfloat16* w2h = (__hip_bfloat16*)(ws + alloc(256 * 1024 * 2));
    __hip_bfloat16* w2l = (__hip_bfloat16*)(ws + alloc(256 * 1024 * 2));
    float* b2 = (float*)(ws + alloc(256 * 4));
    __hip_bfloat16* xh = (__hip_bfloat16*)(ws + alloc((size_t)NBATCH * T_DIM * 512 * 2));
    __hip_bfloat16* xl = (__hip_bfloat16*)(ws + alloc((size_t)NBATCH * T_DIM * 512 * 2));
    __hip_bfloat16* S  = (__hip_bfloat16*)(ws + alloc((size_t)NBATCH * T_DIM * 1024 * 2));
    float* pre = (float*)(ws + alloc((size_t)NBATCH * T_DIM * 1024 * 4));
    (void)ws_size; (void)in_sizes; (void)n_in; (void)out_size;

    // prep weights + x
    prep_w<<<(1024 * 512 + 255) / 256, 256, 0, stream>>>(W0, w0h, w0l, b0, 512, 1024);
    prep_w<<<(1024 * 1024 + 255) / 256, 256, 0, stream>>>(W1, w1h, w1l, b1, 1024, 1024);
    prep_w<<<(256 * 1024 + 255) / 256, 256, 0, stream>>>(W2, w2h, w2l, b2, 1024, 256);
    prep_x<<<dim3(16, 8, 64), dim3(32, 8), 0, stream>>>(x, xh, xl);

    // Layer 1: O=1024, K=512, 3 planes (xh*Wh + xl*Wh + xh*Wl); NT=24, KSHIFT=3
    gemm256<24, 3><<<dim3(256), 512, 0, stream>>>(w0h, w0h, w0l, xh, xl, xh,
                                                  b0, pre, 1024, 4);
    lif_hidden4<<<(NBATCH * 1024 / 4) / 256, 256, 0, stream>>>(pre, S, beta, thr, 1024);

    // Layer 2: O=1024, K=1024, 2 planes (S*Wh + S*Wl); NT=32, KSHIFT=4
    gemm256<32, 4><<<dim3(256), 512, 0, stream>>>(w1h, w1l, w1l, S, S, S,
                                                  b1, pre, 1024, 4);
    lif_hidden4<<<(NBATCH * 1024 / 4) / 256, 256, 0, stream>>>(pre, S, beta, thr, 1024);

    // Layer 3: O=256, K=1024, 2 passes, 128x64 tile -> grid 512 (2 blocks/CU)
    gemm_mfma<64><<<dim3(512), 256, 0, stream>>>(w2h, w2l, w2l, S, S, S,
                                                 b2, pre, 256, 1024, 2, 2, 4);
    lif_final_t<<<dim3(256), 64, 0, stream>>>(pre, out, out + (size_t)NBATCH * 256 * T_DIM,
                                              beta, thr);
}

// Round 7
// 300.457 us; speedup vs baseline: 1.0915x; 1.0915x over previous
//
#include <hip/hip_runtime.h>
#include <hip/hip_bf16.h>
#include <stdint.h>

typedef __attribute__((ext_vector_type(8))) short short8;
typedef __attribute__((ext_vector_type(4))) float f32x4;

#define T_DIM 256
#define NBATCH 64

__device__ __forceinline__ void gload_lds16(const void* g, void* l) {
    __builtin_amdgcn_global_load_lds(
        (const __attribute__((address_space(1))) void*)g,
        (__attribute__((address_space(3))) void*)l, 16, 0, 0);
}

// ---------------- prep: W [(K+1)][O] fp32 -> WT_hi/WT_lo [O][K] bf16 + bias[O] ----
__global__ void prep_w(const float* __restrict__ W, __hip_bfloat16* __restrict__ WTh,
                       __hip_bfloat16* __restrict__ WTl, float* __restrict__ bias,
                       int K, int O) {
    int idx = blockIdx.x * blockDim.x + threadIdx.x;
    int total = O * K;
    if (idx < total) {
        int o = idx / K, i = idx % K;
        float w = W[(size_t)i * O + o];
        __hip_bfloat16 h = __float2bfloat16(w);
        WTh[idx] = h;
        WTl[idx] = __float2bfloat16(w - __bfloat162float(h));
    }
    if (idx < O) bias[idx] = W[(size_t)K * O + idx];
}

// ---------------- prep: x [64][512][256] fp32 -> xh/xl [64][256][512] bf16 --------
__global__ void prep_x(const float* __restrict__ x, __hip_bfloat16* __restrict__ xh,
                       __hip_bfloat16* __restrict__ xl) {
    __shared__ float tile[32][33];
    int b = blockIdx.z;
    int i0 = blockIdx.x * 32;
    int t0 = blockIdx.y * 32;
    int tx = threadIdx.x;
    int ty = threadIdx.y;
    for (int dy = 0; dy < 32; dy += 8)
        tile[ty + dy][tx] = x[((size_t)b * 512 + i0 + ty + dy) * T_DIM + t0 + tx];
    __syncthreads();
    for (int dy = 0; dy < 32; dy += 8) {
        float w = tile[tx][ty + dy];
        size_t dst = ((size_t)b * T_DIM + t0 + ty + dy) * 512 + i0 + tx;
        __hip_bfloat16 h = __float2bfloat16(w);
        xh[dst] = h;
        xl[dst] = __float2bfloat16(w - __bfloat162float(h));
    }
}

// ---------------- 256x256 8-phase counted-vmcnt GEMM (layers 1 & 2) ---------------
// Tile 256(o) x 256(t=all), BK=64, 8 waves (2M x 4N), per-wave 128x64, acc[8][4].
// LDS 128KB: A dbuf{0,1} at 0/32K, B dbuf{0,1} at 64K/96K.
// RACE-FREE STAGGER (slot ledger):
//   B-slots of dbuf[kt&1] are fully read at phase-0's closing barrier -> stage
//   B(kt+2) at q2/q3.  A-slots of dbuf[(kt+1)&1] are fully read at end of tile
//   kt-1 -> stage A(kt+1) at q0/q1.  vmcnt(4) once per tile (before closing
//   barrier of q3) leaves only B(kt+2) in flight, forces A(kt+1)/B(kt+1) landed.
// Accumulation order per output element = ascending (plane, k-tile, kk):
// identical to the 2-barrier kernel -> bit-identical (absmax canary 2.058594).
template <int NT, int KSHIFT>
__global__ __launch_bounds__(512, 2) void gemm8p(
    const __hip_bfloat16* __restrict__ A0, const __hip_bfloat16* __restrict__ A1,
    const __hip_bfloat16* __restrict__ A2,
    const __hip_bfloat16* __restrict__ B0, const __hip_bfloat16* __restrict__ B1,
    const __hip_bfloat16* __restrict__ B2,
    const float* __restrict__ bias, float* __restrict__ Cout,
    int O, int nOx) {
    constexpr int K = 64 << KSHIFT;
    __shared__ __align__(16) char lds[131072];

    const int fid = blockIdx.x;
    const int xcd = fid & 7;
    const int k_in = fid >> 3;
    const int b = xcd * 8 + k_in / nOx;
    const int o0 = (k_in % nOx) * 256;

    const int tid = threadIdx.x;
    const int lane = tid & 63;
    const int wave = tid >> 6;
    const int wm = wave >> 2;    // 0..1 (o)
    const int wn = wave & 3;     // 0..3 (t)

    const int srow = tid >> 3;          // 0..63
    const int skb = (tid & 7) * 16;     // LDS dest byte in 128B row (linear)
    const int src_x = skb ^ ((srow & 7) << 4);  // pre-swizzled global column

    f32x4 acc[8][4] = {};

    // stage one half-tile (2 x gload_lds16/thread). part: 0=Ah0 1=Bh0 2=Ah1 3=Bh1
    auto STAGEH = [&](int kt, int part) {
        if (kt >= NT) return;
        int p = kt >> KSHIFT;
        int k0 = (kt & ((1 << KSHIFT) - 1)) << 6;
        int d = kt & 1;
        int half = part >> 1;
        const __hip_bfloat16* Gq;
        char* base;
        size_t grow;
        if ((part & 1) == 0) {  // A
            Gq = (p == 0) ? A0 : ((p == 1) ? A1 : A2);
            base = (char*)lds + d * 32768;
            grow = (size_t)(o0 + half * 128 + srow);
        } else {               // B
            Gq = (p == 0) ? B0 : ((p == 1) ? B1 : B2);
            base = (char*)lds + 65536 + d * 32768;
            grow = (size_t)b * T_DIM + half * 128 + srow;
        }
        const char* g = (const char*)(Gq + grow * K + k0) + src_x;
        char* dst = base + (half * 128 + srow) * 128 + skb;
        gload_lds16(g, dst);
        gload_lds16(g + (size_t)64 * K * 2, dst + 64 * 128);
    };

    // one K-tile = 4 phases (M-quadrants).  Stagger: q0->A0(kt+1), q1->A1(kt+1),
    // q2->B0(kt+2), q3->B1(kt+2).  wait_n (4/0/-1) before the q3 closing barrier.
    auto KTILE = [&](int kt, int wait_n) {
        const int d = kt & 1;
        const char* Ab = (const char*)lds + d * 32768;
        const char* Bb = (const char*)lds + 65536 + d * 32768;
        short8 bfr[4][2];
#pragma unroll
        for (int q = 0; q < 4; ++q) {
            // ---- ds-read this phase's operands ----
            if (q == 0) {
#pragma unroll
                for (int j = 0; j < 4; ++j) {
                    int row = wn * 64 + j * 16 + (lane & 15);
#pragma unroll
                    for (int kk = 0; kk < 2; ++kk) {
                        int kb = ((((lane >> 4) * 8) + kk * 32) * 2) ^ ((row & 7) << 4);
                        bfr[j][kk] = *(const short8*)(Bb + row * 128 + kb);
                    }
                }
            }
            short8 af[2][2];
#pragma unroll
            for (int i = 0; i < 2; ++i) {
                int row = wm * 128 + (q * 2 + i) * 16 + (lane & 15);
#pragma unroll
                for (int kk = 0; kk < 2; ++kk) {
                    int kb = ((((lane >> 4) * 8) + kk * 32) * 2) ^ ((row & 7) << 4);
                    af[i][kk] = *(const short8*)(Ab + row * 128 + kb);
                }
            }
            // ---- issue this phase's half-tile prefetch (slot-safe stagger) ----
            if (q == 0)      STAGEH(kt + 1, 0);   // A-half0 of next tile
            else if (q == 1) STAGEH(kt + 1, 2);   // A-half1 of next tile
            else if (q == 2) STAGEH(kt + 2, 1);   // B-half0 of tile+2
            else             STAGEH(kt + 2, 3);   // B-half1 of tile+2

            if (q == 0) asm volatile("s_waitcnt lgkmcnt(8)" ::: "memory");
            __builtin_amdgcn_s_barrier();
            asm volatile("s_waitcnt lgkmcnt(0)" ::: "memory");
            __builtin_amdgcn_sched_barrier(0);
            __builtin_amdgcn_s_setprio(1);
#pragma unroll
            for (int kk = 0; kk < 2; ++kk)
#pragma unroll
                for (int i = 0; i < 2; ++i)
#pragma unroll
                    for (int j = 0; j < 4; ++j)
                        acc[q * 2 + i][j] = __builtin_amdgcn_mfma_f32_16x16x32_bf16(
                            af[i][kk], bfr[j][kk], acc[q * 2 + i][j], 0, 0, 0);
            __builtin_amdgcn_s_setprio(0);
            if (q == 3) {
                if (wait_n == 4)
                    asm volatile("s_waitcnt vmcnt(4)" ::: "memory");
                else if (wait_n == 0)
                    asm volatile("s_waitcnt vmcnt(0)" ::: "memory");
            }
            __builtin_amdgcn_s_barrier();
            __builtin_amdgcn_sched_barrier(0);
        }
    };

    // prologue: tile 0 complete + B halves of tile 1 (12 loads); vmcnt(4) leaves
    // the newest 4 (B(1)) in flight, tile 0 fully landed.
    STAGEH(0, 0); STAGEH(0, 2); STAGEH(0, 1); STAGEH(0, 3);
    STAGEH(1, 1); STAGEH(1, 3);
    asm volatile("s_waitcnt vmcnt(4)" ::: "memory");
    __builtin_amdgcn_s_barrier();
    __builtin_amdgcn_sched_barrier(0);

    for (int kt = 0; kt < NT; ++kt)
        KTILE(kt, (kt < NT - 2) ? 4 : ((kt == NT - 2) ? 0 : -1));

    // epilogue: D col(t)=lane&15, row(o)=(lane>>4)*4+r -> float4/lane into [b][t][o]
#pragma unroll
    for (int i = 0; i < 8; ++i) {
        int ob = o0 + wm * 128 + i * 16 + ((lane >> 4) * 4);
        f32x4 bv = *(const f32x4*)(bias + ob);
#pragma unroll
        for (int j = 0; j < 4; ++j) {
            int t = wn * 64 + j * 16 + (lane & 15);
            *(f32x4*)(Cout + ((size_t)b * T_DIM + t) * O + ob) = acc[i][j] + bv;
        }
    }
}

// ---------------- 128 x BN GEMM (layer 3: O=256 needs more blocks) ----------------
template <int BN>
__global__ __launch_bounds__(256) void gemm_mfma(
    const __hip_bfloat16* __restrict__ A0, const __hip_bfloat16* __restrict__ A1,
    const __hip_bfloat16* __restrict__ A2,
    const __hip_bfloat16* __restrict__ B0, const __hip_bfloat16* __restrict__ B1,
    const __hip_bfloat16* __restrict__ B2,
    const float* __restrict__ bias, float* __restrict__ Cout,
    int O, int K, int npass, int nOx, int nTy) {
    constexpr int NB = BN / 32;
    __shared__ __hip_bfloat16 As[128 * 64];
    __shared__ __hip_bfloat16 Bs[BN * 64];

    const int fid = blockIdx.x;
    const int bpb = nOx * nTy;
    const int xcd = fid & 7;
    const int k_in = fid >> 3;
    const int b = xcd * 8 + k_in / bpb;
    const int r_in = k_in % bpb;
    const int o0 = (r_in / nTy) * 128;
    const int t0 = (r_in % nTy) * BN;

    const int tid = threadIdx.x;
    const int lane = tid & 63;
    const int wave = tid >> 6;
    const int wm = wave >> 1, wn = wave & 1;

    const __hip_bfloat16* Ap[3] = {A0, A1, A2};
    const __hip_bfloat16* Bp[3] = {B0, B1, B2};

    f32x4 acc[4][NB] = {};

    const int srow = tid >> 3;
    const int skb  = (tid & 7) * 16;

    for (int p = 0; p < npass; ++p) {
        const __hip_bfloat16* Aptr = Ap[p];
        const __hip_bfloat16* Bptr = Bp[p] + (size_t)b * T_DIM * K;
        for (int k0 = 0; k0 < K; k0 += 64) {
            int src_kb = skb ^ ((srow & 7) << 4);
#pragma unroll
            for (int r = 0; r < 4; ++r) {
                int row = srow + r * 32;
                gload_lds16((const char*)(Aptr + (size_t)(o0 + row) * K + k0) + src_kb,
                            (char*)As + row * 128 + skb);
            }
#pragma unroll
            for (int r = 0; r < NB; ++r) {
                int row = srow + r * 32;
                gload_lds16((const char*)(Bptr + (size_t)(t0 + row) * K + k0) + src_kb,
                            (char*)Bs + row * 128 + skb);
            }
            __syncthreads();
#pragma unroll
            for (int kk = 0; kk < 2; ++kk) {
                short8 af[4], bfr[NB];
#pragma unroll
                for (int i = 0; i < 4; ++i) {
                    int row = wm * 64 + i * 16 + (lane & 15);
                    int kb = ((((lane >> 4) * 8) + kk * 32) * 2) ^ ((row & 7) << 4);
                    af[i] = *(const short8*)((const char*)As + row * 128 + kb);
                }
#pragma unroll
                for (int j = 0; j < NB; ++j) {
                    int row = wn * (BN / 2) + j * 16 + (lane & 15);
                    int kb = ((((lane >> 4) * 8) + kk * 32) * 2) ^ ((row & 7) << 4);
                    bfr[j] = *(const short8*)((const char*)Bs + row * 128 + kb);
                }
#pragma unroll
                for (int i = 0; i < 4; ++i)
#pragma unroll
                    for (int j = 0; j < NB; ++j)
                        acc[i][j] = __builtin_amdgcn_mfma_f32_16x16x32_bf16(
                            af[i], bfr[j], acc[i][j], 0, 0, 0);
            }
            __syncthreads();
        }
    }
#pragma unroll
    for (int i = 0; i < 4; ++i) {
        int ob = o0 + wm * 64 + i * 16 + ((lane >> 4) * 4);
        f32x4 bv = *(const f32x4*)(bias + ob);
#pragma unroll
        for (int j = 0; j < NB; ++j) {
            int t = t0 + wn * (BN / 2) + j * 16 + (lane & 15);
            f32x4 v = acc[i][j] + bv;
            *(f32x4*)(Cout + ((size_t)b * T_DIM + t) * O + ob) = v;
        }
    }
}

// ---------------- LIF scan: hidden layers (thread per neuron, coalesced) ----------
__global__ void lif_hidden(const float* __restrict__ pre, __hip_bfloat16* __restrict__ st,
                           const float* __restrict__ beta_p, const float* __restrict__ thr_p,
                           int O) {
    int idx = blockIdx.x * blockDim.x + threadIdx.x;
    int b = idx / O, o = idx - b * O;
    float sb = 1.f / (1.f + expf(-beta_p[0]));
    float thr = thr_p[0];
    float mem = 0.f;
    const float* src = pre + (size_t)b * T_DIM * O + o;
    __hip_bfloat16* dst = st + (size_t)b * T_DIM * O + o;
    for (int t = 0; t < T_DIM; ++t) {
        float mu = __fadd_rn(__fmul_rn(sb, mem), src[(size_t)t * O]);
        float spike = (mu >= thr) ? 1.f : 0.f;
        mem = mu - spike * thr;
        dst[(size_t)t * O] = __float2bfloat16(spike);
    }
}

// ---------------- LIF scan: final layer (LDS-transposed coalesced writes) ---------
__global__ __launch_bounds__(64) void lif_final_t(
    const float* __restrict__ pre, float* __restrict__ osp, float* __restrict__ omem,
    const float* __restrict__ beta_p, const float* __restrict__ thr_p) {
    __shared__ float spk[64][33];
    __shared__ float mm[64][33];
    int bid = blockIdx.x;
    int b = bid >> 2, og = bid & 3;
    int lane = threadIdx.x;
    float sb = 1.f / (1.f + expf(-beta_p[0]));
    float thr = thr_p[0];
    float mem = 0.f;
    const float* src = pre + (size_t)b * T_DIM * 256 + og * 64 + lane;
    int bo = b * 256 + og * 64;
    for (int c = 0; c < 8; ++c) {
        int t0 = c * 32;
        float xv[32];
#pragma unroll
        for (int tt = 0; tt < 32; ++tt)
            xv[tt] = src[(size_t)(t0 + tt) * 256];
#pragma unroll
        for (int tt = 0; tt < 32; ++tt) {
            mm[lane][tt] = mem;
            float mu = __fadd_rn(__fmul_rn(sb, mem), xv[tt]);
            float spike = (mu >= thr) ? 1.f : 0.f;
            spk[lane][tt] = spike;
            mem = mu - spike * thr;
        }
#pragma unroll
        for (int it = 0; it < 32; ++it) {
            int row = (lane >> 5) + 2 * it;
            int col = lane & 31;
            size_t dst = ((size_t)bo + row) * T_DIM + t0 + col;
            osp[dst] = spk[row][col];
            omem[dst] = mm[row][col];
        }
    }
}

extern "C" void kernel_launch(void* const* d_in, const int* in_sizes, int n_in,
                              void* d_out, int out_size, void* d_ws, size_t ws_size,
                              hipStream_t stream) {
    const float* x  = (const float*)d_in[0];
    const float* W0 = (const float*)d_in[1];
    const float* W1 = (const float*)d_in[2];
    const float* W2 = (const float*)d_in[3];
    const float* beta = (const float*)d_in[4];
    const float* thr  = (const float*)d_in[5];
    float* out = (float*)d_out;

    char* ws = (char*)d_ws;
    size_t off = 0;
    auto alloc = [&](size_t bytes) {
        size_t r = off;
        off = (off + bytes + 255) & ~(size_t)255;
        return r;
    };
    __hip_bfloat16* w0h = (__hip_bfloat16*)(ws + alloc(1024 * 512 * 2));
    __hip_bfloat16* w0l = (__hip_bfloat16*)(ws + alloc(1024 * 512 * 2));
    float* b0 = (float*)(ws + alloc(1024 * 4));
    __hip_bfloat16* w1h = (__hip_bfloat16*)(ws + alloc(1024 * 1024 * 2));
    __hip_bfloat16* w1l = (__hip_bfloat16*)(ws + alloc(1024 * 1024 * 2));
    float* b1 = (float*)(ws + alloc(1024 * 4));
    __hip_bfloat16* w2h = (__hip_bfloat16*)(ws + alloc(256 * 1024 * 2));
    __hip_bfloat16* w2l = (__hip_bfloat16*)(ws + alloc(256 * 1024 * 2));
    float* b2 = (float*)(ws + alloc(256 * 4));
    __hip_bfloat16* xh = (__hip_bfloat16*)(ws + alloc((size_t)NBATCH * T_DIM * 512 * 2));
    __hip_bfloat16* xl = (__hip_bfloat16*)(ws + alloc((size_t)NBATCH * T_DIM * 512 * 2));
    __hip_bfloat16* S  = (__hip_bfloat16*)(ws + alloc((size_t)NBATCH * T_DIM * 1024 * 2));
    float* pre = (float*)(ws + alloc((size_t)NBATCH * T_DIM * 1024 * 4));
    (void)ws_size; (void)in_sizes; (void)n_in; (void)out_size;

    prep_w<<<(1024 * 512 + 255) / 256, 256, 0, stream>>>(W0, w0h, w0l, b0, 512, 1024);
    prep_w<<<(1024 * 1024 + 255) / 256, 256, 0, stream>>>(W1, w1h, w1l, b1, 1024, 1024);
    prep_w<<<(256 * 1024 + 255) / 256, 256, 0, stream>>>(W2, w2h, w2l, b2, 1024, 256);
    prep_x<<<dim3(16, 8, 64), dim3(32, 8), 0, stream>>>(x, xh, xl);

    // Layer 1: O=1024, K=512, 3 planes (xh*Wh + xl*Wh + xh*Wl); NT=24
    gemm8p<24, 3><<<dim3(256), 512, 0, stream>>>(w0h, w0h, w0l, xh, xl, xh,
                                                 b0, pre, 1024, 4);
    lif_hidden<<<(NBATCH * 1024) / 256, 256, 0, stream>>>(pre, S, beta, thr, 1024);

    // Layer 2: O=1024, K=1024, 2 planes (S*Wh + S*Wl); NT=32
    gemm8p<32, 4><<<dim3(256), 512, 0, stream>>>(w1h, w1l, w1l, S, S, S,
                                                 b1, pre, 1024, 4);
    lif_hidden<<<(NBATCH * 1024) / 256, 256, 0, stream>>>(pre, S, beta, thr, 1024);

    // Layer 3: O=256, K=1024, 2 passes, 128x64 tile -> grid 512 (2 blocks/CU)
    gemm_mfma<64><<<dim3(512), 256, 0, stream>>>(w2h, w2l, w2l, S, S, S,
                                                 b2, pre, 256, 1024, 2, 2, 4);
    lif_final_t<<<dim3(256), 64, 0, stream>>>(pre, out, out + (size_t)NBATCH * 256 * T_DIM,
                                              beta, thr);
}